// Round 9
// baseline (213.428 us; speedup 1.0000x reference)
//
#include <hip/hip_runtime.h>
#include <hip/hip_bf16.h>

constexpr int B = 4, N = 8192, S = 2048;

typedef __attribute__((ext_vector_type(8))) short short8;
typedef __attribute__((ext_vector_type(4))) float v4f;

__device__ inline float u2f(ushort u) {
    union { ushort u; __hip_bfloat16 h; } c; c.u = u; return __bfloat162float(c.h);
}
__device__ inline ushort f2u(float f) {
    union { ushort u; __hip_bfloat16 h; } c; c.h = __float2bfloat16(f); return c.u;
}
__device__ inline void async_lds16(const void* g, void* l) {
    __builtin_amdgcn_global_load_lds(
        (const __attribute__((address_space(1))) unsigned*)g,
        (__attribute__((address_space(3))) unsigned*)l, 16, 0, 0);
}
__device__ inline short8 ld8(const ushort* p) { return *(const short8*)p; }

// deterministic distance: identical codegen in both knn passes
__device__ inline float dist2f(float4 p, float x1, float y1, float z1, float t1) {
    float dot = fmaf(x1, p.x, fmaf(y1, p.y, z1 * p.z));
    return fmaf(-2.f, dot, t1) + p.w;
}

// ----------------- prep: repack W to chunk-major [kk][q][o][8] bf16 -------
__global__ __launch_bounds__(256) void prep_kernel(
    const float* __restrict__ W1, const float* __restrict__ W2,
    __hip_bfloat16* __restrict__ W1r, __hip_bfloat16* __restrict__ W2r,
    float* __restrict__ zero_region)
{
    int i = blockIdx.x * 256 + threadIdx.x;
    if (i < 12288) {
        int kk = i >> 10, q = (i >> 8) & 3, o = i & 255;
        const float* src = W1 + o * 384 + kk * 32 + q * 8;
        float4 a = *(const float4*)src, b = *(const float4*)(src + 4);
        union { short8 s; ushort u[8]; } pk;
        pk.u[0] = f2u(a.x); pk.u[1] = f2u(a.y); pk.u[2] = f2u(a.z); pk.u[3] = f2u(a.w);
        pk.u[4] = f2u(b.x); pk.u[5] = f2u(b.y); pk.u[6] = f2u(b.z); pk.u[7] = f2u(b.w);
        *(short8*)((ushort*)W1r + i * 8) = pk.s;
    } else if (i < 20480) {
        int u = i - 12288;
        int kk = u >> 10, q = (u >> 8) & 3, o = u & 255;
        const float* src = W2 + o * 256 + kk * 32 + q * 8;
        float4 a = *(const float4*)src, b = *(const float4*)(src + 4);
        union { short8 s; ushort u[8]; } pk;
        pk.u[0] = f2u(a.x); pk.u[1] = f2u(a.y); pk.u[2] = f2u(a.z); pk.u[3] = f2u(a.w);
        pk.u[4] = f2u(b.x); pk.u[5] = f2u(b.y); pk.u[6] = f2u(b.z); pk.u[7] = f2u(b.w);
        *(short8*)((ushort*)W2r + u * 8) = pk.s;
    } else if (i < 21504) {
        zero_region[i - 20480] = 0.f;
    }
}

// ---------------------------------------------------------------- 3-NN ----
// Two-pass: (A) distance-only top-3 via min/med3 (3 VALU/insert, no masks);
// (B) index recovery — only candidates with dd <= global-3rd enter a rare
// branchy insert. Exact top_k semantics: pass B keeps per-lane stability
// ('<' with increasing indices), cross-lane merge is (d,idx)-lexicographic.
__global__ __launch_bounds__(256) void knn_kernel(
    const float* __restrict__ pos1, const float* __restrict__ pos2,
    float* __restrict__ wgt, int* __restrict__ idxb)
{
    __shared__ float4 p2s[S];
    const int b = blockIdx.y;
    for (int s = threadIdx.x; s < S; s += 256) {
        float x = pos2[(b * 3 + 0) * S + s];
        float y = pos2[(b * 3 + 1) * S + s];
        float z = pos2[(b * 3 + 2) * S + s];
        p2s[s] = make_float4(x, y, z, x * x + y * y + z * z);
    }
    __syncthreads();

    const int qi = blockIdx.x * 16 + (threadIdx.x >> 4);
    const int lp = threadIdx.x & 15;
    const float x1 = pos1[(b * 3 + 0) * N + qi];
    const float y1 = pos1[(b * 3 + 1) * N + qi];
    const float z1 = pos1[(b * 3 + 2) * N + qi];
    const float t1 = x1 * x1 + y1 * y1 + z1 * z1;

    // ---- Pass A: distances only ----
    float d0 = 3.4e38f, d1 = 3.4e38f, d2 = 3.4e38f;
    #pragma unroll 4
    for (int tt = 0; tt < S / 16; ++tt) {
        float dd = dist2f(p2s[16 * tt + lp], x1, y1, z1, t1);
        float a1 = __builtin_amdgcn_fmed3f(dd, d0, d1);
        float a2 = __builtin_amdgcn_fmed3f(dd, d1, d2);
        d0 = fminf(d0, dd);
        d1 = a1; d2 = a2;
    }
    #pragma unroll
    for (int m = 1; m <= 8; m <<= 1) {
        float e0 = __shfl_xor(d0, m), e1 = __shfl_xor(d1, m), e2 = __shfl_xor(d2, m);
        float es[3] = {e0, e1, e2};
        #pragma unroll
        for (int k = 0; k < 3; ++k) {
            float e = es[k];
            float a1 = __builtin_amdgcn_fmed3f(e, d0, d1);
            float a2 = __builtin_amdgcn_fmed3f(e, d1, d2);
            d0 = fminf(d0, e);
            d1 = a1; d2 = a2;
        }
    }
    const float d2g = d2;

    // ---- Pass B: recover indices (rare insert) ----
    float f0 = 3.4e38f, f1 = 3.4e38f, f2 = 3.4e38f;
    int i0 = 0x7fffffff, i1 = 0x7fffffff, i2 = 0x7fffffff;
    for (int tt = 0; tt < S / 16; ++tt) {
        int s = 16 * tt + lp;
        float dd = dist2f(p2s[s], x1, y1, z1, t1);
        if (dd <= d2g) {
            bool c0 = dd < f0, c1 = dd < f1, c2 = dd < f2;
            f2 = c1 ? f1 : (c2 ? dd : f2);
            i2 = c1 ? i1 : (c2 ? s : i2);
            f1 = c0 ? f0 : (c1 ? dd : f1);
            i1 = c0 ? i0 : (c1 ? s : i1);
            f0 = c0 ? dd : f0;
            i0 = c0 ? s : i0;
        }
    }

    // cross-lane lexicographic merge of (f, i)
    #pragma unroll
    for (int m = 1; m <= 8; m <<= 1) {
        float c0 = __shfl_xor(f0, m), c1 = __shfl_xor(f1, m), c2 = __shfl_xor(f2, m);
        int   j0 = __shfl_xor(i0, m), j1 = __shfl_xor(i1, m), j2 = __shfl_xor(i2, m);
        float cd[3] = {c0, c1, c2};
        int   cj[3] = {j0, j1, j2};
        #pragma unroll
        for (int k = 0; k < 3; ++k) {
            float d = cd[k]; int id = cj[k];
            bool l0 = (d < f0) || (d == f0 && id < i0);
            bool l1 = (d < f1) || (d == f1 && id < i1);
            bool l2 = (d < f2) || (d == f2 && id < i2);
            if (l0)      { f2 = f1; i2 = i1; f1 = f0; i1 = i0; f0 = d; i0 = id; }
            else if (l1) { f2 = f1; i2 = i1; f1 = d; i1 = id; }
            else if (l2) { f2 = d; i2 = id; }
        }
    }

    if (lp == 0) {
        float w0 = 1.f / fmaxf(f0, 1e-10f);
        float w1 = 1.f / fmaxf(f1, 1e-10f);
        float w2 = 1.f / fmaxf(f2, 1e-10f);
        float inv = 1.f / (w0 + w1 + w2);
        i0 = ((unsigned)i0 < S) ? i0 : 0;
        i1 = ((unsigned)i1 < S) ? i1 : 0;
        i2 = ((unsigned)i2 < S) ? i2 : 0;
        int base = (b * N + qi) * 3;
        wgt[base + 0] = w0 * inv; wgt[base + 1] = w1 * inv; wgt[base + 2] = w2 * inv;
        idxb[base + 0] = i0; idxb[base + 1] = i1; idxb[base + 2] = i2;
    }
}

// --------------------------------------------------------- transpose -----
__global__ __launch_bounds__(256) void transpose_k(
    const float* __restrict__ in, __hip_bfloat16* __restrict__ out,
    int L, int C)
{
    __shared__ ushort tl[64][66];
    const int b = blockIdx.z;
    const int l0 = blockIdx.x * 64, c0 = blockIdx.y * 64;
    const int t = threadIdx.x;
    const float* ip = in + (size_t)b * C * L;
    const int lr = t & 63, cb = t >> 6;
    #pragma unroll
    for (int i = 0; i < 16; ++i) {
        int c = cb + 4 * i;
        tl[lr][c] = f2u(ip[(size_t)(c0 + c) * L + l0 + lr]);
    }
    __syncthreads();
    ushort* op = (ushort*)out + (size_t)b * L * C;
    const int cp = t & 31, lrow = t >> 5;
    #pragma unroll
    for (int i = 0; i < 8; ++i) {
        int l = lrow + 8 * i;
        ushort2 v;
        v.x = tl[l][2 * cp];
        v.y = tl[l][2 * cp + 1];
        *(ushort2*)(op + (size_t)(l0 + l) * C + c0 + 2 * cp) = v;
    }
}

// ------------------------------------------------ GEMM1 (fused interp) ----
__global__ __launch_bounds__(256) void gemm1_kernel(
    const __hip_bfloat16* __restrict__ Wr, const float* __restrict__ bias,
    const __hip_bfloat16* __restrict__ f2T, const __hip_bfloat16* __restrict__ f1T,
    const int* __restrict__ idxb, const float* __restrict__ wgt,
    __hip_bfloat16* __restrict__ y, float* __restrict__ sums)
{
    __shared__ __align__(16) ushort Xs[64 * 384];      // 48 KB
    __shared__ __align__(16) ushort Wbuf[2 * 8192];    // 32 KB
    const int t = threadIdx.x;
    const int b = blockIdx.y;
    const int n0 = blockIdx.x * 64;
    const int w = t >> 6, lane = t & 63;
    const int q = lane >> 4, r = lane & 15, r7 = r & 7;

    {
        const char* g0 = (const char*)Wr;
        #pragma unroll
        for (int jj = 0; jj < 4; ++jj)
            async_lds16(g0 + jj * 4096 + t * 16,
                        (char*)Wbuf + jj * 4096 + w * 1024);
    }

    {
        const int lp = t & 31, ro = t >> 5;
        #pragma unroll
        for (int it = 0; it < 8; ++it) {
            int rr = ro + 8 * it;
            int base = (b * N + n0 + rr) * 3;
            int s0 = idxb[base], s1 = idxb[base + 1], s2 = idxb[base + 2];
            s0 = ((unsigned)s0 < S) ? s0 : 0;
            s1 = ((unsigned)s1 < S) ? s1 : 0;
            s2 = ((unsigned)s2 < S) ? s2 : 0;
            float w0 = wgt[base], w1 = wgt[base + 1], w2 = wgt[base + 2];
            union { short8 s; ushort u[8]; } a, c, d, o;
            a.s = ld8((const ushort*)f2T + ((size_t)b * S + s0) * 256 + 8 * lp);
            c.s = ld8((const ushort*)f2T + ((size_t)b * S + s1) * 256 + 8 * lp);
            d.s = ld8((const ushort*)f2T + ((size_t)b * S + s2) * 256 + 8 * lp);
            #pragma unroll
            for (int j = 0; j < 8; ++j)
                o.u[j] = f2u(w0 * u2f(a.u[j]) + w1 * u2f(c.u[j]) + w2 * u2f(d.u[j]));
            *(short8*)(Xs + rr * 384 + ((lp ^ ro) * 8)) = o.s;
        }
    }
    {
        const int lp = t & 15, ro = t >> 4;
        #pragma unroll
        for (int it = 0; it < 4; ++it) {
            int rr = ro + 16 * it;
            short8 v = ld8((const ushort*)f1T + ((size_t)b * N + n0 + rr) * 128 + 8 * lp);
            int c = 32 + lp;
            *(short8*)(Xs + rr * 384 + ((c ^ (rr & 7)) * 8)) = v;
        }
    }
    __syncthreads();

    v4f acc[4][4];
    #pragma unroll
    for (int mt = 0; mt < 4; ++mt)
        #pragma unroll
        for (int nf = 0; nf < 4; ++nf) acc[mt][nf] = (v4f){0.f, 0.f, 0.f, 0.f};

    for (int kk = 0; kk < 12; ++kk) {
        if (kk < 11) {
            const char* g = (const char*)Wr + (kk + 1) * 16384;
            char* l = (char*)Wbuf + ((kk + 1) & 1) * 16384;
            #pragma unroll
            for (int jj = 0; jj < 4; ++jj)
                async_lds16(g + jj * 4096 + t * 16, l + jj * 4096 + w * 1024);
        }
        const ushort* Wb = Wbuf + (kk & 1) * 8192;
        short8 af[4], bf[4];
        #pragma unroll
        for (int mt = 0; mt < 4; ++mt)
            af[mt] = ld8(Wb + q * 2048 + (w * 64 + mt * 16 + r) * 8);
        #pragma unroll
        for (int nf = 0; nf < 4; ++nf)
            bf[nf] = ld8(Xs + (nf * 16 + r) * 384 + (((kk * 4 + q) ^ r7) * 8));
        #pragma unroll
        for (int mt = 0; mt < 4; ++mt)
            #pragma unroll
            for (int nf = 0; nf < 4; ++nf)
                acc[mt][nf] = __builtin_amdgcn_mfma_f32_16x16x32_bf16(
                    af[mt], bf[nf], acc[mt][nf], 0, 0, 0);
        __syncthreads();
    }

    float* statS = (float*)Xs;
    float* statQ = statS + 256;
    #pragma unroll
    for (int mt = 0; mt < 4; ++mt) {
        int ob = w * 64 + mt * 16 + q * 4;
        float4 bi = *(const float4*)(bias + ob);
        float sj0 = 0, sj1 = 0, sj2 = 0, sj3 = 0;
        float qj0 = 0, qj1 = 0, qj2 = 0, qj3 = 0;
        #pragma unroll
        for (int nf = 0; nf < 4; ++nf) {
            int n = n0 + nf * 16 + r;
            float v0 = acc[mt][nf][0] + bi.x, v1 = acc[mt][nf][1] + bi.y;
            float v2 = acc[mt][nf][2] + bi.z, v3 = acc[mt][nf][3] + bi.w;
            ushort4 pk; pk.x = f2u(v0); pk.y = f2u(v1); pk.z = f2u(v2); pk.w = f2u(v3);
            *(ushort4*)((ushort*)y + ((size_t)b * N + n) * 256 + ob) = pk;
            sj0 += v0; sj1 += v1; sj2 += v2; sj3 += v3;
            qj0 += v0 * v0; qj1 += v1 * v1; qj2 += v2 * v2; qj3 += v3 * v3;
        }
        #pragma unroll
        for (int m = 1; m <= 8; m <<= 1) {
            sj0 += __shfl_xor(sj0, m); sj1 += __shfl_xor(sj1, m);
            sj2 += __shfl_xor(sj2, m); sj3 += __shfl_xor(sj3, m);
            qj0 += __shfl_xor(qj0, m); qj1 += __shfl_xor(qj1, m);
            qj2 += __shfl_xor(qj2, m); qj3 += __shfl_xor(qj3, m);
        }
        if (r == 0) {
            statS[ob + 0] = sj0; statS[ob + 1] = sj1;
            statS[ob + 2] = sj2; statS[ob + 3] = sj3;
            statQ[ob + 0] = qj0; statQ[ob + 1] = qj1;
            statQ[ob + 2] = qj2; statQ[ob + 3] = qj3;
        }
    }
    __syncthreads();
    atomicAdd(&sums[t], statS[t]);
    atomicAdd(&sums[256 + t], statQ[t]);
}

// ------------------------ GEMM2 (BN1+ReLU on load, in-place, fused stats) --
__global__ __launch_bounds__(256) void gemm2_kernel(
    const __hip_bfloat16* __restrict__ Wr, const float* __restrict__ bias,
    const float* __restrict__ sums1, const float* __restrict__ g1,
    const float* __restrict__ be1,
    __hip_bfloat16* __restrict__ y, float* __restrict__ sums)
{
    __shared__ __align__(16) ushort Xs[64 * 256];      // 32 KB
    __shared__ __align__(16) ushort Wbuf[2 * 8192];    // 32 KB
    __shared__ float ssA[256], ssB[256];
    const int t = threadIdx.x;
    const int b = blockIdx.y;
    const int n0 = blockIdx.x * 64;
    const int w = t >> 6, lane = t & 63;
    const int q = lane >> 4, r = lane & 15, r7 = r & 7;

    {
        const char* g0 = (const char*)Wr;
        #pragma unroll
        for (int jj = 0; jj < 4; ++jj)
            async_lds16(g0 + jj * 4096 + t * 16,
                        (char*)Wbuf + jj * 4096 + w * 1024);
    }

    {
        float sv = sums1[t], qv = sums1[256 + t];
        float mean = sv * (1.f / 32768.f);
        float var = qv * (1.f / 32768.f) - mean * mean;
        float rstd = rsqrtf(var + 1e-5f);
        float sc = g1[t] * rstd;
        ssA[t] = sc;
        ssB[t] = be1[t] - mean * sc;
    }
    __syncthreads();

    {
        const int lp = t & 31, ro = t >> 5;
        #pragma unroll
        for (int it = 0; it < 8; ++it) {
            int rr = ro + 8 * it;
            union { short8 s; ushort u[8]; } v, o;
            v.s = ld8((const ushort*)y + ((size_t)b * N + n0 + rr) * 256 + 8 * lp);
            #pragma unroll
            for (int j = 0; j < 8; ++j)
                o.u[j] = f2u(fmaxf(u2f(v.u[j]) * ssA[8 * lp + j] + ssB[8 * lp + j], 0.f));
            *(short8*)(Xs + rr * 256 + ((lp ^ ro) * 8)) = o.s;
        }
    }
    __syncthreads();

    v4f acc[4][4];
    #pragma unroll
    for (int mt = 0; mt < 4; ++mt)
        #pragma unroll
        for (int nf = 0; nf < 4; ++nf) acc[mt][nf] = (v4f){0.f, 0.f, 0.f, 0.f};

    for (int kk = 0; kk < 8; ++kk) {
        if (kk < 7) {
            const char* g = (const char*)Wr + (kk + 1) * 16384;
            char* l = (char*)Wbuf + ((kk + 1) & 1) * 16384;
            #pragma unroll
            for (int jj = 0; jj < 4; ++jj)
                async_lds16(g + jj * 4096 + t * 16, l + jj * 4096 + w * 1024);
        }
        const ushort* Wb = Wbuf + (kk & 1) * 8192;
        short8 af[4], bf[4];
        #pragma unroll
        for (int mt = 0; mt < 4; ++mt)
            af[mt] = ld8(Wb + q * 2048 + (w * 64 + mt * 16 + r) * 8);
        #pragma unroll
        for (int nf = 0; nf < 4; ++nf)
            bf[nf] = ld8(Xs + (nf * 16 + r) * 256 + (((kk * 4 + q) ^ r7) * 8));
        #pragma unroll
        for (int mt = 0; mt < 4; ++mt)
            #pragma unroll
            for (int nf = 0; nf < 4; ++nf)
                acc[mt][nf] = __builtin_amdgcn_mfma_f32_16x16x32_bf16(
                    af[mt], bf[nf], acc[mt][nf], 0, 0, 0);
        __syncthreads();
    }

    float* statS = (float*)Xs;
    float* statQ = statS + 256;
    #pragma unroll
    for (int mt = 0; mt < 4; ++mt) {
        int ob = w * 64 + mt * 16 + q * 4;
        float4 bi = *(const float4*)(bias + ob);
        float sj0 = 0, sj1 = 0, sj2 = 0, sj3 = 0;
        float qj0 = 0, qj1 = 0, qj2 = 0, qj3 = 0;
        #pragma unroll
        for (int nf = 0; nf < 4; ++nf) {
            int n = n0 + nf * 16 + r;
            float v0 = acc[mt][nf][0] + bi.x, v1 = acc[mt][nf][1] + bi.y;
            float v2 = acc[mt][nf][2] + bi.z, v3 = acc[mt][nf][3] + bi.w;
            ushort4 pk; pk.x = f2u(v0); pk.y = f2u(v1); pk.z = f2u(v2); pk.w = f2u(v3);
            *(ushort4*)((ushort*)y + ((size_t)b * N + n) * 256 + ob) = pk;
            sj0 += v0; sj1 += v1; sj2 += v2; sj3 += v3;
            qj0 += v0 * v0; qj1 += v1 * v1; qj2 += v2 * v2; qj3 += v3 * v3;
        }
        #pragma unroll
        for (int m = 1; m <= 8; m <<= 1) {
            sj0 += __shfl_xor(sj0, m); sj1 += __shfl_xor(sj1, m);
            sj2 += __shfl_xor(sj2, m); sj3 += __shfl_xor(sj3, m);
            qj0 += __shfl_xor(qj0, m); qj1 += __shfl_xor(qj1, m);
            qj2 += __shfl_xor(qj2, m); qj3 += __shfl_xor(qj3, m);
        }
        if (r == 0) {
            statS[ob + 0] = sj0; statS[ob + 1] = sj1;
            statS[ob + 2] = sj2; statS[ob + 3] = sj3;
            statQ[ob + 0] = qj0; statQ[ob + 1] = qj1;
            statQ[ob + 2] = qj2; statQ[ob + 3] = qj3;
        }
    }
    __syncthreads();
    atomicAdd(&sums[t], statS[t]);
    atomicAdd(&sums[256 + t], statQ[t]);
}

// ------------- final: BN2+ReLU + transpose to [B,256,N] fp32 (64x64) ------
__global__ __launch_bounds__(256) void final_kernel(
    const __hip_bfloat16* __restrict__ Y, const float* __restrict__ sums2,
    const float* __restrict__ g2, const float* __restrict__ be2,
    float* __restrict__ out)
{
    __shared__ float tl[64][65];
    __shared__ float ssA[64], ssB[64];
    const int t = threadIdx.x;
    const int b = blockIdx.z;
    const int n0 = blockIdx.x * 64, c0 = blockIdx.y * 64;

    if (t < 64) {
        int c = c0 + t;
        float sv = sums2[c], qv = sums2[256 + c];
        float mean = sv * (1.f / 32768.f);
        float var = qv * (1.f / 32768.f) - mean * mean;
        float rstd = rsqrtf(var + 1e-5f);
        float sc = g2[c] * rstd;
        ssA[t] = sc;
        ssB[t] = be2[c] - mean * sc;
    }
    __syncthreads();

    const int nl = t >> 3, cho = 8 * (t & 7);
    #pragma unroll
    for (int it = 0; it < 2; ++it) {
        int n = nl + 32 * it;
        union { short8 s; ushort u[8]; } v;
        v.s = ld8((const ushort*)Y + ((size_t)b * N + n0 + n) * 256 + c0 + cho);
        #pragma unroll
        for (int j = 0; j < 8; ++j)
            tl[n][cho + j] = fmaxf(u2f(v.u[j]) * ssA[cho + j] + ssB[cho + j], 0.f);
    }
    __syncthreads();

    const int cl = t >> 4, n4 = (t & 15) * 4;
    #pragma unroll
    for (int it = 0; it < 4; ++it) {
        int c = cl + 16 * it;
        float4 v;
        v.x = tl[n4 + 0][c]; v.y = tl[n4 + 1][c];
        v.z = tl[n4 + 2][c]; v.w = tl[n4 + 3][c];
        *(float4*)(out + ((size_t)b * 256 + c0 + c) * N + n0 + n4) = v;
    }
}

// ------------------------------------------------------------ launch -----
extern "C" void kernel_launch(void* const* d_in, const int* in_sizes, int n_in,
                              void* d_out, int out_size, void* d_ws, size_t ws_size,
                              hipStream_t stream)
{
    (void)in_sizes; (void)n_in; (void)out_size;
    if (ws_size < (30u << 20)) return;

    const float* pos1 = (const float*)d_in[0];
    const float* pos2 = (const float*)d_in[1];
    const float* f1   = (const float*)d_in[2];
    const float* f2   = (const float*)d_in[3];
    const float* W1   = (const float*)d_in[4];
    const float* b1   = (const float*)d_in[5];
    const float* g1   = (const float*)d_in[6];
    const float* be1  = (const float*)d_in[7];
    const float* W2   = (const float*)d_in[8];
    const float* b2   = (const float*)d_in[9];
    const float* g2   = (const float*)d_in[10];
    const float* be2  = (const float*)d_in[11];

    char* ws = (char*)d_ws;
    int*   idxb  = (int*)(ws + 0);
    float* wgt   = (float*)(ws + 393216);
    float* sums1 = (float*)(ws + 786432);
    float* sums2 = sums1 + 512;
    __hip_bfloat16* W1r = (__hip_bfloat16*)(ws + 819200);
    __hip_bfloat16* W2r = (__hip_bfloat16*)(ws + 1015808);
    __hip_bfloat16* f2T = (__hip_bfloat16*)(ws + (2u << 20));
    __hip_bfloat16* f1T = (__hip_bfloat16*)(ws + (6u << 20));
    __hip_bfloat16* y   = (__hip_bfloat16*)(ws + (14u << 20));

    prep_kernel<<<84, 256, 0, stream>>>(W1, W2, W1r, W2r, sums1);

    knn_kernel<<<dim3(N / 16, B), 256, 0, stream>>>(pos1, pos2, wgt, idxb);

    transpose_k<<<dim3(S / 64, 256 / 64, B), 256, 0, stream>>>(f2, f2T, S, 256);
    transpose_k<<<dim3(N / 64, 128 / 64, B), 256, 0, stream>>>(f1, f1T, N, 128);

    gemm1_kernel<<<dim3(N / 64, B), 256, 0, stream>>>(
        W1r, b1, f2T, f1T, idxb, wgt, y, sums1);
    gemm2_kernel<<<dim3(N / 64, B), 256, 0, stream>>>(
        W2r, b2, sums1, g1, be1, y, sums2);
    final_kernel<<<dim3(N / 64, 256 / 64, B), 256, 0, stream>>>(
        y, sums2, g2, be2, (float*)d_out);
}

// Round 10
// 210.164 us; speedup vs baseline: 1.0155x; 1.0155x over previous
//
#include <hip/hip_runtime.h>
#include <hip/hip_bf16.h>

constexpr int B = 4, N = 8192, S = 2048;

typedef __attribute__((ext_vector_type(8))) short short8;
typedef __attribute__((ext_vector_type(4))) float v4f;

__device__ inline float u2f(ushort u) {
    union { ushort u; __hip_bfloat16 h; } c; c.u = u; return __bfloat162float(c.h);
}
__device__ inline ushort f2u(float f) {
    union { ushort u; __hip_bfloat16 h; } c; c.h = __float2bfloat16(f); return c.u;
}
__device__ inline void async_lds16(const void* g, void* l) {
    __builtin_amdgcn_global_load_lds(
        (const __attribute__((address_space(1))) unsigned*)g,
        (__attribute__((address_space(3))) unsigned*)l, 16, 0, 0);
}
__device__ inline short8 ld8(const ushort* p) { return *(const short8*)p; }

// ----------------- prep: repack W to chunk-major [kk][q][o][8] bf16 -------
__global__ __launch_bounds__(256) void prep_kernel(
    const float* __restrict__ W1, const float* __restrict__ W2,
    __hip_bfloat16* __restrict__ W1r, __hip_bfloat16* __restrict__ W2r,
    float* __restrict__ zero_region)
{
    int i = blockIdx.x * 256 + threadIdx.x;
    if (i < 12288) {
        int kk = i >> 10, q = (i >> 8) & 3, o = i & 255;
        const float* src = W1 + o * 384 + kk * 32 + q * 8;
        float4 a = *(const float4*)src, b = *(const float4*)(src + 4);
        union { short8 s; ushort u[8]; } pk;
        pk.u[0] = f2u(a.x); pk.u[1] = f2u(a.y); pk.u[2] = f2u(a.z); pk.u[3] = f2u(a.w);
        pk.u[4] = f2u(b.x); pk.u[5] = f2u(b.y); pk.u[6] = f2u(b.z); pk.u[7] = f2u(b.w);
        *(short8*)((ushort*)W1r + i * 8) = pk.s;
    } else if (i < 20480) {
        int u = i - 12288;
        int kk = u >> 10, q = (u >> 8) & 3, o = u & 255;
        const float* src = W2 + o * 256 + kk * 32 + q * 8;
        float4 a = *(const float4*)src, b = *(const float4*)(src + 4);
        union { short8 s; ushort u[8]; } pk;
        pk.u[0] = f2u(a.x); pk.u[1] = f2u(a.y); pk.u[2] = f2u(a.z); pk.u[3] = f2u(a.w);
        pk.u[4] = f2u(b.x); pk.u[5] = f2u(b.y); pk.u[6] = f2u(b.z); pk.u[7] = f2u(b.w);
        *(short8*)((ushort*)W2r + u * 8) = pk.s;
    } else if (i < 21504) {
        zero_region[i - 20480] = 0.f;
    }
}

// ---------------------------------------------------------------- 3-NN ----
// Lanes = queries (64/wave). Candidates are wave-uniform SGPR broadcasts
// (s_load of pos2 rows) -> ZERO LDS traffic in the scan. 4 waves/block each
// scan a 512-candidate chunk; 4-way lexicographic merge via small LDS.
// Top-3 insert: 3 cmp + 5 cndmask (indices) + min/2*med3 (exact fp32 dists).
__global__ __launch_bounds__(256) void knn_kernel(
    const float* __restrict__ pos1, const float* __restrict__ pos2,
    float* __restrict__ wgt, int* __restrict__ idxb)
{
    __shared__ float dLs[4][64][3];
    __shared__ int   iLs[4][64][3];
    const int b = blockIdx.y;
    const int t = threadIdx.x;
    const int lane = t & 63;
    const int w = __builtin_amdgcn_readfirstlane(t >> 6);   // SGPR: chunk id
    const int qi = blockIdx.x * 64 + lane;

    const float x1 = pos1[(b * 3 + 0) * N + qi];
    const float y1 = pos1[(b * 3 + 1) * N + qi];
    const float z1 = pos1[(b * 3 + 2) * N + qi];

    const float* __restrict__ px = pos2 + (b * 3 + 0) * S + w * 512;
    const float* __restrict__ py = pos2 + (b * 3 + 1) * S + w * 512;
    const float* __restrict__ pz = pos2 + (b * 3 + 2) * S + w * 512;

    float d0 = 3.4e38f, d1 = 3.4e38f, d2 = 3.4e38f;
    int i0 = 0x7fffffff, i1 = 0x7fffffff, i2 = 0x7fffffff;

    #pragma unroll 8
    for (int i = 0; i < 512; ++i) {
        float qx = px[i], qy = py[i], qz = pz[i];   // uniform -> s_load
        float dx = x1 - qx, dy = y1 - qy, dz = z1 - qz;
        float dd = fmaf(dx, dx, fmaf(dy, dy, dz * dz));
        int s = w * 512 + i;
        bool c0 = dd < d0, c1 = dd < d1, c2 = dd < d2;
        i2 = c1 ? i1 : (c2 ? s : i2);
        i1 = c0 ? i0 : (c1 ? s : i1);
        i0 = c0 ? s : i0;
        float nd1 = __builtin_amdgcn_fmed3f(dd, d0, d1);
        float nd2 = __builtin_amdgcn_fmed3f(dd, d1, d2);
        d0 = fminf(d0, dd);
        d1 = nd1; d2 = nd2;
    }

    dLs[w][lane][0] = d0; dLs[w][lane][1] = d1; dLs[w][lane][2] = d2;
    iLs[w][lane][0] = i0; iLs[w][lane][1] = i1; iLs[w][lane][2] = i2;
    __syncthreads();

    if (t < 64) {
        float f0 = dLs[0][t][0], f1 = dLs[0][t][1], f2 = dLs[0][t][2];
        int   j0 = iLs[0][t][0], j1 = iLs[0][t][1], j2 = iLs[0][t][2];
        #pragma unroll
        for (int c = 1; c < 4; ++c) {
            #pragma unroll
            for (int k = 0; k < 3; ++k) {
                float d = dLs[c][t][k]; int id = iLs[c][t][k];
                bool l0 = (d < f0) || (d == f0 && id < j0);
                bool l1 = (d < f1) || (d == f1 && id < j1);
                bool l2 = (d < f2) || (d == f2 && id < j2);
                if (l0)      { f2 = f1; j2 = j1; f1 = f0; j1 = j0; f0 = d; j0 = id; }
                else if (l1) { f2 = f1; j2 = j1; f1 = d; j1 = id; }
                else if (l2) { f2 = d; j2 = id; }
            }
        }
        float w0 = 1.f / fmaxf(f0, 1e-10f);
        float w1 = 1.f / fmaxf(f1, 1e-10f);
        float w2 = 1.f / fmaxf(f2, 1e-10f);
        float inv = 1.f / (w0 + w1 + w2);
        j0 = ((unsigned)j0 < S) ? j0 : 0;
        j1 = ((unsigned)j1 < S) ? j1 : 0;
        j2 = ((unsigned)j2 < S) ? j2 : 0;
        int base = (b * N + blockIdx.x * 64 + t) * 3;
        wgt[base + 0] = w0 * inv; wgt[base + 1] = w1 * inv; wgt[base + 2] = w2 * inv;
        idxb[base + 0] = j0; idxb[base + 1] = j1; idxb[base + 2] = j2;
    }
}

// --------------------------------------------------------- transpose -----
__global__ __launch_bounds__(256) void transpose_k(
    const float* __restrict__ in, __hip_bfloat16* __restrict__ out,
    int L, int C)
{
    __shared__ ushort tl[64][66];
    const int b = blockIdx.z;
    const int l0 = blockIdx.x * 64, c0 = blockIdx.y * 64;
    const int t = threadIdx.x;
    const float* ip = in + (size_t)b * C * L;
    const int lr = t & 63, cb = t >> 6;
    #pragma unroll
    for (int i = 0; i < 16; ++i) {
        int c = cb + 4 * i;
        tl[lr][c] = f2u(ip[(size_t)(c0 + c) * L + l0 + lr]);
    }
    __syncthreads();
    ushort* op = (ushort*)out + (size_t)b * L * C;
    const int cp = t & 31, lrow = t >> 5;
    #pragma unroll
    for (int i = 0; i < 8; ++i) {
        int l = lrow + 8 * i;
        ushort2 v;
        v.x = tl[l][2 * cp];
        v.y = tl[l][2 * cp + 1];
        *(ushort2*)(op + (size_t)(l0 + l) * C + c0 + 2 * cp) = v;
    }
}

// ------------------------------------------------ GEMM1 (fused interp) ----
__global__ __launch_bounds__(256) void gemm1_kernel(
    const __hip_bfloat16* __restrict__ Wr, const float* __restrict__ bias,
    const __hip_bfloat16* __restrict__ f2T, const __hip_bfloat16* __restrict__ f1T,
    const int* __restrict__ idxb, const float* __restrict__ wgt,
    __hip_bfloat16* __restrict__ y, float* __restrict__ sums)
{
    __shared__ __align__(16) ushort Xs[64 * 384];      // 48 KB
    __shared__ __align__(16) ushort Wbuf[2 * 8192];    // 32 KB
    const int t = threadIdx.x;
    const int b = blockIdx.y;
    const int n0 = blockIdx.x * 64;
    const int w = t >> 6, lane = t & 63;
    const int q = lane >> 4, r = lane & 15, r7 = r & 7;

    {
        const char* g0 = (const char*)Wr;
        #pragma unroll
        for (int jj = 0; jj < 4; ++jj)
            async_lds16(g0 + jj * 4096 + t * 16,
                        (char*)Wbuf + jj * 4096 + w * 1024);
    }

    {
        const int lp = t & 31, ro = t >> 5;
        #pragma unroll
        for (int it = 0; it < 8; ++it) {
            int rr = ro + 8 * it;
            int base = (b * N + n0 + rr) * 3;
            int s0 = idxb[base], s1 = idxb[base + 1], s2 = idxb[base + 2];
            s0 = ((unsigned)s0 < S) ? s0 : 0;
            s1 = ((unsigned)s1 < S) ? s1 : 0;
            s2 = ((unsigned)s2 < S) ? s2 : 0;
            float w0 = wgt[base], w1 = wgt[base + 1], w2 = wgt[base + 2];
            union { short8 s; ushort u[8]; } a, c, d, o;
            a.s = ld8((const ushort*)f2T + ((size_t)b * S + s0) * 256 + 8 * lp);
            c.s = ld8((const ushort*)f2T + ((size_t)b * S + s1) * 256 + 8 * lp);
            d.s = ld8((const ushort*)f2T + ((size_t)b * S + s2) * 256 + 8 * lp);
            #pragma unroll
            for (int j = 0; j < 8; ++j)
                o.u[j] = f2u(w0 * u2f(a.u[j]) + w1 * u2f(c.u[j]) + w2 * u2f(d.u[j]));
            *(short8*)(Xs + rr * 384 + ((lp ^ ro) * 8)) = o.s;
        }
    }
    {
        const int lp = t & 15, ro = t >> 4;
        #pragma unroll
        for (int it = 0; it < 4; ++it) {
            int rr = ro + 16 * it;
            short8 v = ld8((const ushort*)f1T + ((size_t)b * N + n0 + rr) * 128 + 8 * lp);
            int c = 32 + lp;
            *(short8*)(Xs + rr * 384 + ((c ^ (rr & 7)) * 8)) = v;
        }
    }
    __syncthreads();

    v4f acc[4][4];
    #pragma unroll
    for (int mt = 0; mt < 4; ++mt)
        #pragma unroll
        for (int nf = 0; nf < 4; ++nf) acc[mt][nf] = (v4f){0.f, 0.f, 0.f, 0.f};

    for (int kk = 0; kk < 12; ++kk) {
        if (kk < 11) {
            const char* g = (const char*)Wr + (kk + 1) * 16384;
            char* l = (char*)Wbuf + ((kk + 1) & 1) * 16384;
            #pragma unroll
            for (int jj = 0; jj < 4; ++jj)
                async_lds16(g + jj * 4096 + t * 16, l + jj * 4096 + w * 1024);
        }
        const ushort* Wb = Wbuf + (kk & 1) * 8192;
        short8 af[4], bf[4];
        #pragma unroll
        for (int mt = 0; mt < 4; ++mt)
            af[mt] = ld8(Wb + q * 2048 + (w * 64 + mt * 16 + r) * 8);
        #pragma unroll
        for (int nf = 0; nf < 4; ++nf)
            bf[nf] = ld8(Xs + (nf * 16 + r) * 384 + (((kk * 4 + q) ^ r7) * 8));
        #pragma unroll
        for (int mt = 0; mt < 4; ++mt)
            #pragma unroll
            for (int nf = 0; nf < 4; ++nf)
                acc[mt][nf] = __builtin_amdgcn_mfma_f32_16x16x32_bf16(
                    af[mt], bf[nf], acc[mt][nf], 0, 0, 0);
        __syncthreads();
    }

    float* statS = (float*)Xs;
    float* statQ = statS + 256;
    #pragma unroll
    for (int mt = 0; mt < 4; ++mt) {
        int ob = w * 64 + mt * 16 + q * 4;
        float4 bi = *(const float4*)(bias + ob);
        float sj0 = 0, sj1 = 0, sj2 = 0, sj3 = 0;
        float qj0 = 0, qj1 = 0, qj2 = 0, qj3 = 0;
        #pragma unroll
        for (int nf = 0; nf < 4; ++nf) {
            int n = n0 + nf * 16 + r;
            float v0 = acc[mt][nf][0] + bi.x, v1 = acc[mt][nf][1] + bi.y;
            float v2 = acc[mt][nf][2] + bi.z, v3 = acc[mt][nf][3] + bi.w;
            ushort4 pk; pk.x = f2u(v0); pk.y = f2u(v1); pk.z = f2u(v2); pk.w = f2u(v3);
            *(ushort4*)((ushort*)y + ((size_t)b * N + n) * 256 + ob) = pk;
            sj0 += v0; sj1 += v1; sj2 += v2; sj3 += v3;
            qj0 += v0 * v0; qj1 += v1 * v1; qj2 += v2 * v2; qj3 += v3 * v3;
        }
        #pragma unroll
        for (int m = 1; m <= 8; m <<= 1) {
            sj0 += __shfl_xor(sj0, m); sj1 += __shfl_xor(sj1, m);
            sj2 += __shfl_xor(sj2, m); sj3 += __shfl_xor(sj3, m);
            qj0 += __shfl_xor(qj0, m); qj1 += __shfl_xor(qj1, m);
            qj2 += __shfl_xor(qj2, m); qj3 += __shfl_xor(qj3, m);
        }
        if (r == 0) {
            statS[ob + 0] = sj0; statS[ob + 1] = sj1;
            statS[ob + 2] = sj2; statS[ob + 3] = sj3;
            statQ[ob + 0] = qj0; statQ[ob + 1] = qj1;
            statQ[ob + 2] = qj2; statQ[ob + 3] = qj3;
        }
    }
    __syncthreads();
    atomicAdd(&sums[t], statS[t]);
    atomicAdd(&sums[256 + t], statQ[t]);
}

// ------------------------ GEMM2 (BN1+ReLU on load, in-place, fused stats) --
__global__ __launch_bounds__(256) void gemm2_kernel(
    const __hip_bfloat16* __restrict__ Wr, const float* __restrict__ bias,
    const float* __restrict__ sums1, const float* __restrict__ g1,
    const float* __restrict__ be1,
    __hip_bfloat16* __restrict__ y, float* __restrict__ sums)
{
    __shared__ __align__(16) ushort Xs[64 * 256];      // 32 KB
    __shared__ __align__(16) ushort Wbuf[2 * 8192];    // 32 KB
    __shared__ float ssA[256], ssB[256];
    const int t = threadIdx.x;
    const int b = blockIdx.y;
    const int n0 = blockIdx.x * 64;
    const int w = t >> 6, lane = t & 63;
    const int q = lane >> 4, r = lane & 15, r7 = r & 7;

    {
        const char* g0 = (const char*)Wr;
        #pragma unroll
        for (int jj = 0; jj < 4; ++jj)
            async_lds16(g0 + jj * 4096 + t * 16,
                        (char*)Wbuf + jj * 4096 + w * 1024);
    }

    {
        float sv = sums1[t], qv = sums1[256 + t];
        float mean = sv * (1.f / 32768.f);
        float var = qv * (1.f / 32768.f) - mean * mean;
        float rstd = rsqrtf(var + 1e-5f);
        float sc = g1[t] * rstd;
        ssA[t] = sc;
        ssB[t] = be1[t] - mean * sc;
    }
    __syncthreads();

    {
        const int lp = t & 31, ro = t >> 5;
        #pragma unroll
        for (int it = 0; it < 8; ++it) {
            int rr = ro + 8 * it;
            union { short8 s; ushort u[8]; } v, o;
            v.s = ld8((const ushort*)y + ((size_t)b * N + n0 + rr) * 256 + 8 * lp);
            #pragma unroll
            for (int j = 0; j < 8; ++j)
                o.u[j] = f2u(fmaxf(u2f(v.u[j]) * ssA[8 * lp + j] + ssB[8 * lp + j], 0.f));
            *(short8*)(Xs + rr * 256 + ((lp ^ ro) * 8)) = o.s;
        }
    }
    __syncthreads();

    v4f acc[4][4];
    #pragma unroll
    for (int mt = 0; mt < 4; ++mt)
        #pragma unroll
        for (int nf = 0; nf < 4; ++nf) acc[mt][nf] = (v4f){0.f, 0.f, 0.f, 0.f};

    for (int kk = 0; kk < 8; ++kk) {
        if (kk < 7) {
            const char* g = (const char*)Wr + (kk + 1) * 16384;
            char* l = (char*)Wbuf + ((kk + 1) & 1) * 16384;
            #pragma unroll
            for (int jj = 0; jj < 4; ++jj)
                async_lds16(g + jj * 4096 + t * 16, l + jj * 4096 + w * 1024);
        }
        const ushort* Wb = Wbuf + (kk & 1) * 8192;
        short8 af[4], bf[4];
        #pragma unroll
        for (int mt = 0; mt < 4; ++mt)
            af[mt] = ld8(Wb + q * 2048 + (w * 64 + mt * 16 + r) * 8);
        #pragma unroll
        for (int nf = 0; nf < 4; ++nf)
            bf[nf] = ld8(Xs + (nf * 16 + r) * 256 + (((kk * 4 + q) ^ r7) * 8));
        #pragma unroll
        for (int mt = 0; mt < 4; ++mt)
            #pragma unroll
            for (int nf = 0; nf < 4; ++nf)
                acc[mt][nf] = __builtin_amdgcn_mfma_f32_16x16x32_bf16(
                    af[mt], bf[nf], acc[mt][nf], 0, 0, 0);
        __syncthreads();
    }

    float* statS = (float*)Xs;
    float* statQ = statS + 256;
    #pragma unroll
    for (int mt = 0; mt < 4; ++mt) {
        int ob = w * 64 + mt * 16 + q * 4;
        float4 bi = *(const float4*)(bias + ob);
        float sj0 = 0, sj1 = 0, sj2 = 0, sj3 = 0;
        float qj0 = 0, qj1 = 0, qj2 = 0, qj3 = 0;
        #pragma unroll
        for (int nf = 0; nf < 4; ++nf) {
            int n = n0 + nf * 16 + r;
            float v0 = acc[mt][nf][0] + bi.x, v1 = acc[mt][nf][1] + bi.y;
            float v2 = acc[mt][nf][2] + bi.z, v3 = acc[mt][nf][3] + bi.w;
            ushort4 pk; pk.x = f2u(v0); pk.y = f2u(v1); pk.z = f2u(v2); pk.w = f2u(v3);
            *(ushort4*)((ushort*)y + ((size_t)b * N + n) * 256 + ob) = pk;
            sj0 += v0; sj1 += v1; sj2 += v2; sj3 += v3;
            qj0 += v0 * v0; qj1 += v1 * v1; qj2 += v2 * v2; qj3 += v3 * v3;
        }
        #pragma unroll
        for (int m = 1; m <= 8; m <<= 1) {
            sj0 += __shfl_xor(sj0, m); sj1 += __shfl_xor(sj1, m);
            sj2 += __shfl_xor(sj2, m); sj3 += __shfl_xor(sj3, m);
            qj0 += __shfl_xor(qj0, m); qj1 += __shfl_xor(qj1, m);
            qj2 += __shfl_xor(qj2, m); qj3 += __shfl_xor(qj3, m);
        }
        if (r == 0) {
            statS[ob + 0] = sj0; statS[ob + 1] = sj1;
            statS[ob + 2] = sj2; statS[ob + 3] = sj3;
            statQ[ob + 0] = qj0; statQ[ob + 1] = qj1;
            statQ[ob + 2] = qj2; statQ[ob + 3] = qj3;
        }
    }
    __syncthreads();
    atomicAdd(&sums[t], statS[t]);
    atomicAdd(&sums[256 + t], statQ[t]);
}

// ------------- final: BN2+ReLU + transpose to [B,256,N] fp32 (64x64) ------
__global__ __launch_bounds__(256) void final_kernel(
    const __hip_bfloat16* __restrict__ Y, const float* __restrict__ sums2,
    const float* __restrict__ g2, const float* __restrict__ be2,
    float* __restrict__ out)
{
    __shared__ float tl[64][65];
    __shared__ float ssA[64], ssB[64];
    const int t = threadIdx.x;
    const int b = blockIdx.z;
    const int n0 = blockIdx.x * 64, c0 = blockIdx.y * 64;

    if (t < 64) {
        int c = c0 + t;
        float sv = sums2[c], qv = sums2[256 + c];
        float mean = sv * (1.f / 32768.f);
        float var = qv * (1.f / 32768.f) - mean * mean;
        float rstd = rsqrtf(var + 1e-5f);
        float sc = g2[c] * rstd;
        ssA[t] = sc;
        ssB[t] = be2[c] - mean * sc;
    }
    __syncthreads();

    const int nl = t >> 3, cho = 8 * (t & 7);
    #pragma unroll
    for (int it = 0; it < 2; ++it) {
        int n = nl + 32 * it;
        union { short8 s; ushort u[8]; } v;
        v.s = ld8((const ushort*)Y + ((size_t)b * N + n0 + n) * 256 + c0 + cho);
        #pragma unroll
        for (int j = 0; j < 8; ++j)
            tl[n][cho + j] = fmaxf(u2f(v.u[j]) * ssA[cho + j] + ssB[cho + j], 0.f);
    }
    __syncthreads();

    const int cl = t >> 4, n4 = (t & 15) * 4;
    #pragma unroll
    for (int it = 0; it < 4; ++it) {
        int c = cl + 16 * it;
        float4 v;
        v.x = tl[n4 + 0][c]; v.y = tl[n4 + 1][c];
        v.z = tl[n4 + 2][c]; v.w = tl[n4 + 3][c];
        *(float4*)(out + ((size_t)b * 256 + c0 + c) * N + n0 + n4) = v;
    }
}

// ------------------------------------------------------------ launch -----
extern "C" void kernel_launch(void* const* d_in, const int* in_sizes, int n_in,
                              void* d_out, int out_size, void* d_ws, size_t ws_size,
                              hipStream_t stream)
{
    (void)in_sizes; (void)n_in; (void)out_size;
    if (ws_size < (30u << 20)) return;

    const float* pos1 = (const float*)d_in[0];
    const float* pos2 = (const float*)d_in[1];
    const float* f1   = (const float*)d_in[2];
    const float* f2   = (const float*)d_in[3];
    const float* W1   = (const float*)d_in[4];
    const float* b1   = (const float*)d_in[5];
    const float* g1   = (const float*)d_in[6];
    const float* be1  = (const float*)d_in[7];
    const float* W2   = (const float*)d_in[8];
    const float* b2   = (const float*)d_in[9];
    const float* g2   = (const float*)d_in[10];
    const float* be2  = (const float*)d_in[11];

    char* ws = (char*)d_ws;
    int*   idxb  = (int*)(ws + 0);
    float* wgt   = (float*)(ws + 393216);
    float* sums1 = (float*)(ws + 786432);
    float* sums2 = sums1 + 512;
    __hip_bfloat16* W1r = (__hip_bfloat16*)(ws + 819200);
    __hip_bfloat16* W2r = (__hip_bfloat16*)(ws + 1015808);
    __hip_bfloat16* f2T = (__hip_bfloat16*)(ws + (2u << 20));
    __hip_bfloat16* f1T = (__hip_bfloat16*)(ws + (6u << 20));
    __hip_bfloat16* y   = (__hip_bfloat16*)(ws + (14u << 20));

    prep_kernel<<<84, 256, 0, stream>>>(W1, W2, W1r, W2r, sums1);

    knn_kernel<<<dim3(N / 64, B), 256, 0, stream>>>(pos1, pos2, wgt, idxb);

    transpose_k<<<dim3(S / 64, 256 / 64, B), 256, 0, stream>>>(f2, f2T, S, 256);
    transpose_k<<<dim3(N / 64, 128 / 64, B), 256, 0, stream>>>(f1, f1T, N, 128);

    gemm1_kernel<<<dim3(N / 64, B), 256, 0, stream>>>(
        W1r, b1, f2T, f1T, idxb, wgt, y, sums1);
    gemm2_kernel<<<dim3(N / 64, B), 256, 0, stream>>>(
        W2r, b2, sums1, g1, be1, y, sums2);
    final_kernel<<<dim3(N / 64, 256 / 64, B), 256, 0, stream>>>(
        y, sums2, g2, be2, (float*)d_out);
}

// Round 11
// 200.659 us; speedup vs baseline: 1.0636x; 1.0474x over previous
//
#include <hip/hip_runtime.h>
#include <hip/hip_bf16.h>

constexpr int B = 4, N = 8192, S = 2048;

typedef __attribute__((ext_vector_type(8))) short short8;
typedef __attribute__((ext_vector_type(4))) float v4f;

__device__ inline float u2f(ushort u) {
    union { ushort u; __hip_bfloat16 h; } c; c.u = u; return __bfloat162float(c.h);
}
__device__ inline ushort f2u(float f) {
    union { ushort u; __hip_bfloat16 h; } c; c.h = __float2bfloat16(f); return c.u;
}
__device__ inline void async_lds16(const void* g, void* l) {
    __builtin_amdgcn_global_load_lds(
        (const __attribute__((address_space(1))) unsigned*)g,
        (__attribute__((address_space(3))) unsigned*)l, 16, 0, 0);
}
__device__ inline short8 ld8(const ushort* p) { return *(const short8*)p; }

// ------- prep: repack W to chunk-major bf16 + pack pos2 as float4 ---------
__global__ __launch_bounds__(256) void prep_kernel(
    const float* __restrict__ W1, const float* __restrict__ W2,
    const float* __restrict__ pos2,
    __hip_bfloat16* __restrict__ W1r, __hip_bfloat16* __restrict__ W2r,
    float4* __restrict__ p2pack, float* __restrict__ zero_region)
{
    int i = blockIdx.x * 256 + threadIdx.x;
    if (i < 12288) {
        int kk = i >> 10, q = (i >> 8) & 3, o = i & 255;
        const float* src = W1 + o * 384 + kk * 32 + q * 8;
        float4 a = *(const float4*)src, b = *(const float4*)(src + 4);
        union { short8 s; ushort u[8]; } pk;
        pk.u[0] = f2u(a.x); pk.u[1] = f2u(a.y); pk.u[2] = f2u(a.z); pk.u[3] = f2u(a.w);
        pk.u[4] = f2u(b.x); pk.u[5] = f2u(b.y); pk.u[6] = f2u(b.z); pk.u[7] = f2u(b.w);
        *(short8*)((ushort*)W1r + i * 8) = pk.s;
    } else if (i < 20480) {
        int u = i - 12288;
        int kk = u >> 10, q = (u >> 8) & 3, o = u & 255;
        const float* src = W2 + o * 256 + kk * 32 + q * 8;
        float4 a = *(const float4*)src, b = *(const float4*)(src + 4);
        union { short8 s; ushort u[8]; } pk;
        pk.u[0] = f2u(a.x); pk.u[1] = f2u(a.y); pk.u[2] = f2u(a.z); pk.u[3] = f2u(a.w);
        pk.u[4] = f2u(b.x); pk.u[5] = f2u(b.y); pk.u[6] = f2u(b.z); pk.u[7] = f2u(b.w);
        *(short8*)((ushort*)W2r + u * 8) = pk.s;
    } else if (i < 21504) {
        zero_region[i - 20480] = 0.f;
    } else if (i < 21504 + B * S) {
        int u = i - 21504;                 // b*S + s
        int b = u >> 11, s = u & (S - 1);
        float x = pos2[(b * 3 + 0) * S + s];
        float y = pos2[(b * 3 + 1) * S + s];
        float z = pos2[(b * 3 + 2) * S + s];
        p2pack[u] = make_float4(x, y, z, x * x + y * y + z * z);
    }
}

// ---------------------------------------------------------------- 3-NN ----
// Lanes = queries (64/wave). Candidates are wave-uniform s_load_dwordx4 of
// packed pos2 -> zero LDS/VMEM in the scan. 8 waves/block each scan a
// 256-candidate chunk; 8-way lexicographic merge via small LDS.
__global__ __launch_bounds__(512) void knn_kernel(
    const float* __restrict__ pos1, const float4* __restrict__ p2pack,
    float* __restrict__ wgt, int* __restrict__ idxb)
{
    __shared__ float dLs[8][64][3];
    __shared__ int   iLs[8][64][3];
    const int b = blockIdx.y;
    const int t = threadIdx.x;
    const int lane = t & 63;
    const int w = __builtin_amdgcn_readfirstlane(t >> 6);   // SGPR: chunk id 0..7
    const int qi = blockIdx.x * 64 + lane;

    const float x1 = pos1[(b * 3 + 0) * N + qi];
    const float y1 = pos1[(b * 3 + 1) * N + qi];
    const float z1 = pos1[(b * 3 + 2) * N + qi];
    const float t1 = x1 * x1 + y1 * y1 + z1 * z1;

    const float4* __restrict__ pp = p2pack + b * S + w * 256;

    float d0 = 3.4e38f, d1 = 3.4e38f, d2 = 3.4e38f;
    int i0 = 0x7fffffff, i1 = 0x7fffffff, i2 = 0x7fffffff;

    #pragma unroll 8
    for (int i = 0; i < 256; ++i) {
        float4 p = pp[i];                               // uniform -> s_load_dwordx4
        float dot = fmaf(x1, p.x, fmaf(y1, p.y, z1 * p.z));
        float dd = fmaf(-2.f, dot, t1) + p.w;
        int s = w * 256 + i;
        bool c0 = dd < d0, c1 = dd < d1, c2 = dd < d2;
        i2 = c1 ? i1 : (c2 ? s : i2);
        i1 = c0 ? i0 : (c1 ? s : i1);
        i0 = c0 ? s : i0;
        float nd1 = __builtin_amdgcn_fmed3f(dd, d0, d1);
        float nd2 = __builtin_amdgcn_fmed3f(dd, d1, d2);
        d0 = fminf(d0, dd);
        d1 = nd1; d2 = nd2;
    }

    dLs[w][lane][0] = d0; dLs[w][lane][1] = d1; dLs[w][lane][2] = d2;
    iLs[w][lane][0] = i0; iLs[w][lane][1] = i1; iLs[w][lane][2] = i2;
    __syncthreads();

    if (t < 64) {
        float f0 = dLs[0][t][0], f1 = dLs[0][t][1], f2 = dLs[0][t][2];
        int   j0 = iLs[0][t][0], j1 = iLs[0][t][1], j2 = iLs[0][t][2];
        #pragma unroll
        for (int c = 1; c < 8; ++c) {
            #pragma unroll
            for (int k = 0; k < 3; ++k) {
                float d = dLs[c][t][k]; int id = iLs[c][t][k];
                bool l0 = (d < f0) || (d == f0 && id < j0);
                bool l1 = (d < f1) || (d == f1 && id < j1);
                bool l2 = (d < f2) || (d == f2 && id < j2);
                if (l0)      { f2 = f1; j2 = j1; f1 = f0; j1 = j0; f0 = d; j0 = id; }
                else if (l1) { f2 = f1; j2 = j1; f1 = d; j1 = id; }
                else if (l2) { f2 = d; j2 = id; }
            }
        }
        float w0 = 1.f / fmaxf(f0, 1e-10f);
        float w1 = 1.f / fmaxf(f1, 1e-10f);
        float w2 = 1.f / fmaxf(f2, 1e-10f);
        float inv = 1.f / (w0 + w1 + w2);
        j0 = ((unsigned)j0 < S) ? j0 : 0;
        j1 = ((unsigned)j1 < S) ? j1 : 0;
        j2 = ((unsigned)j2 < S) ? j2 : 0;
        int base = (b * N + blockIdx.x * 64 + t) * 3;
        wgt[base + 0] = w0 * inv; wgt[base + 1] = w1 * inv; wgt[base + 2] = w2 * inv;
        idxb[base + 0] = j0; idxb[base + 1] = j1; idxb[base + 2] = j2;
    }
}

// --------------------------------------------------------- transpose -----
__global__ __launch_bounds__(256) void transpose_k(
    const float* __restrict__ in, __hip_bfloat16* __restrict__ out,
    int L, int C)
{
    __shared__ ushort tl[64][66];
    const int b = blockIdx.z;
    const int l0 = blockIdx.x * 64, c0 = blockIdx.y * 64;
    const int t = threadIdx.x;
    const float* ip = in + (size_t)b * C * L;
    const int lr = t & 63, cb = t >> 6;
    #pragma unroll
    for (int i = 0; i < 16; ++i) {
        int c = cb + 4 * i;
        tl[lr][c] = f2u(ip[(size_t)(c0 + c) * L + l0 + lr]);
    }
    __syncthreads();
    ushort* op = (ushort*)out + (size_t)b * L * C;
    const int cp = t & 31, lrow = t >> 5;
    #pragma unroll
    for (int i = 0; i < 8; ++i) {
        int l = lrow + 8 * i;
        ushort2 v;
        v.x = tl[l][2 * cp];
        v.y = tl[l][2 * cp + 1];
        *(ushort2*)(op + (size_t)(l0 + l) * C + c0 + 2 * cp) = v;
    }
}

// ------------------------------------------------ GEMM1 (fused interp) ----
__global__ __launch_bounds__(256) void gemm1_kernel(
    const __hip_bfloat16* __restrict__ Wr, const float* __restrict__ bias,
    const __hip_bfloat16* __restrict__ f2T, const __hip_bfloat16* __restrict__ f1T,
    const int* __restrict__ idxb, const float* __restrict__ wgt,
    __hip_bfloat16* __restrict__ y, float* __restrict__ sums)
{
    __shared__ __align__(16) ushort Xs[64 * 384];      // 48 KB
    __shared__ __align__(16) ushort Wbuf[2 * 8192];    // 32 KB
    const int t = threadIdx.x;
    const int b = blockIdx.y;
    const int n0 = blockIdx.x * 64;
    const int w = t >> 6, lane = t & 63;
    const int q = lane >> 4, r = lane & 15, r7 = r & 7;

    {
        const char* g0 = (const char*)Wr;
        #pragma unroll
        for (int jj = 0; jj < 4; ++jj)
            async_lds16(g0 + jj * 4096 + t * 16,
                        (char*)Wbuf + jj * 4096 + w * 1024);
    }

    {
        const int lp = t & 31, ro = t >> 5;
        #pragma unroll
        for (int it = 0; it < 8; ++it) {
            int rr = ro + 8 * it;
            int base = (b * N + n0 + rr) * 3;
            int s0 = idxb[base], s1 = idxb[base + 1], s2 = idxb[base + 2];
            s0 = ((unsigned)s0 < S) ? s0 : 0;
            s1 = ((unsigned)s1 < S) ? s1 : 0;
            s2 = ((unsigned)s2 < S) ? s2 : 0;
            float w0 = wgt[base], w1 = wgt[base + 1], w2 = wgt[base + 2];
            union { short8 s; ushort u[8]; } a, c, d, o;
            a.s = ld8((const ushort*)f2T + ((size_t)b * S + s0) * 256 + 8 * lp);
            c.s = ld8((const ushort*)f2T + ((size_t)b * S + s1) * 256 + 8 * lp);
            d.s = ld8((const ushort*)f2T + ((size_t)b * S + s2) * 256 + 8 * lp);
            #pragma unroll
            for (int j = 0; j < 8; ++j)
                o.u[j] = f2u(w0 * u2f(a.u[j]) + w1 * u2f(c.u[j]) + w2 * u2f(d.u[j]));
            *(short8*)(Xs + rr * 384 + ((lp ^ ro) * 8)) = o.s;
        }
    }
    {
        const int lp = t & 15, ro = t >> 4;
        #pragma unroll
        for (int it = 0; it < 4; ++it) {
            int rr = ro + 16 * it;
            short8 v = ld8((const ushort*)f1T + ((size_t)b * N + n0 + rr) * 128 + 8 * lp);
            int c = 32 + lp;
            *(short8*)(Xs + rr * 384 + ((c ^ (rr & 7)) * 8)) = v;
        }
    }
    __syncthreads();

    v4f acc[4][4];
    #pragma unroll
    for (int mt = 0; mt < 4; ++mt)
        #pragma unroll
        for (int nf = 0; nf < 4; ++nf) acc[mt][nf] = (v4f){0.f, 0.f, 0.f, 0.f};

    for (int kk = 0; kk < 12; ++kk) {
        if (kk < 11) {
            const char* g = (const char*)Wr + (kk + 1) * 16384;
            char* l = (char*)Wbuf + ((kk + 1) & 1) * 16384;
            #pragma unroll
            for (int jj = 0; jj < 4; ++jj)
                async_lds16(g + jj * 4096 + t * 16, l + jj * 4096 + w * 1024);
        }
        const ushort* Wb = Wbuf + (kk & 1) * 8192;
        short8 af[4], bf[4];
        #pragma unroll
        for (int mt = 0; mt < 4; ++mt)
            af[mt] = ld8(Wb + q * 2048 + (w * 64 + mt * 16 + r) * 8);
        #pragma unroll
        for (int nf = 0; nf < 4; ++nf)
            bf[nf] = ld8(Xs + (nf * 16 + r) * 384 + (((kk * 4 + q) ^ r7) * 8));
        #pragma unroll
        for (int mt = 0; mt < 4; ++mt)
            #pragma unroll
            for (int nf = 0; nf < 4; ++nf)
                acc[mt][nf] = __builtin_amdgcn_mfma_f32_16x16x32_bf16(
                    af[mt], bf[nf], acc[mt][nf], 0, 0, 0);
        __syncthreads();
    }

    float* statS = (float*)Xs;
    float* statQ = statS + 256;
    #pragma unroll
    for (int mt = 0; mt < 4; ++mt) {
        int ob = w * 64 + mt * 16 + q * 4;
        float4 bi = *(const float4*)(bias + ob);
        float sj0 = 0, sj1 = 0, sj2 = 0, sj3 = 0;
        float qj0 = 0, qj1 = 0, qj2 = 0, qj3 = 0;
        #pragma unroll
        for (int nf = 0; nf < 4; ++nf) {
            int n = n0 + nf * 16 + r;
            float v0 = acc[mt][nf][0] + bi.x, v1 = acc[mt][nf][1] + bi.y;
            float v2 = acc[mt][nf][2] + bi.z, v3 = acc[mt][nf][3] + bi.w;
            ushort4 pk; pk.x = f2u(v0); pk.y = f2u(v1); pk.z = f2u(v2); pk.w = f2u(v3);
            *(ushort4*)((ushort*)y + ((size_t)b * N + n) * 256 + ob) = pk;
            sj0 += v0; sj1 += v1; sj2 += v2; sj3 += v3;
            qj0 += v0 * v0; qj1 += v1 * v1; qj2 += v2 * v2; qj3 += v3 * v3;
        }
        #pragma unroll
        for (int m = 1; m <= 8; m <<= 1) {
            sj0 += __shfl_xor(sj0, m); sj1 += __shfl_xor(sj1, m);
            sj2 += __shfl_xor(sj2, m); sj3 += __shfl_xor(sj3, m);
            qj0 += __shfl_xor(qj0, m); qj1 += __shfl_xor(qj1, m);
            qj2 += __shfl_xor(qj2, m); qj3 += __shfl_xor(qj3, m);
        }
        if (r == 0) {
            statS[ob + 0] = sj0; statS[ob + 1] = sj1;
            statS[ob + 2] = sj2; statS[ob + 3] = sj3;
            statQ[ob + 0] = qj0; statQ[ob + 1] = qj1;
            statQ[ob + 2] = qj2; statQ[ob + 3] = qj3;
        }
    }
    __syncthreads();
    atomicAdd(&sums[t], statS[t]);
    atomicAdd(&sums[256 + t], statQ[t]);
}

// ------------------------ GEMM2 (BN1+ReLU on load, in-place, fused stats) --
__global__ __launch_bounds__(256) void gemm2_kernel(
    const __hip_bfloat16* __restrict__ Wr, const float* __restrict__ bias,
    const float* __restrict__ sums1, const float* __restrict__ g1,
    const float* __restrict__ be1,
    __hip_bfloat16* __restrict__ y, float* __restrict__ sums)
{
    __shared__ __align__(16) ushort Xs[64 * 256];      // 32 KB
    __shared__ __align__(16) ushort Wbuf[2 * 8192];    // 32 KB
    __shared__ float ssA[256], ssB[256];
    const int t = threadIdx.x;
    const int b = blockIdx.y;
    const int n0 = blockIdx.x * 64;
    const int w = t >> 6, lane = t & 63;
    const int q = lane >> 4, r = lane & 15, r7 = r & 7;

    {
        const char* g0 = (const char*)Wr;
        #pragma unroll
        for (int jj = 0; jj < 4; ++jj)
            async_lds16(g0 + jj * 4096 + t * 16,
                        (char*)Wbuf + jj * 4096 + w * 1024);
    }

    {
        float sv = sums1[t], qv = sums1[256 + t];
        float mean = sv * (1.f / 32768.f);
        float var = qv * (1.f / 32768.f) - mean * mean;
        float rstd = rsqrtf(var + 1e-5f);
        float sc = g1[t] * rstd;
        ssA[t] = sc;
        ssB[t] = be1[t] - mean * sc;
    }
    __syncthreads();

    {
        const int lp = t & 31, ro = t >> 5;
        #pragma unroll
        for (int it = 0; it < 8; ++it) {
            int rr = ro + 8 * it;
            union { short8 s; ushort u[8]; } v, o;
            v.s = ld8((const ushort*)y + ((size_t)b * N + n0 + rr) * 256 + 8 * lp);
            #pragma unroll
            for (int j = 0; j < 8; ++j)
                o.u[j] = f2u(fmaxf(u2f(v.u[j]) * ssA[8 * lp + j] + ssB[8 * lp + j], 0.f));
            *(short8*)(Xs + rr * 256 + ((lp ^ ro) * 8)) = o.s;
        }
    }
    __syncthreads();

    v4f acc[4][4];
    #pragma unroll
    for (int mt = 0; mt < 4; ++mt)
        #pragma unroll
        for (int nf = 0; nf < 4; ++nf) acc[mt][nf] = (v4f){0.f, 0.f, 0.f, 0.f};

    for (int kk = 0; kk < 8; ++kk) {
        if (kk < 7) {
            const char* g = (const char*)Wr + (kk + 1) * 16384;
            char* l = (char*)Wbuf + ((kk + 1) & 1) * 16384;
            #pragma unroll
            for (int jj = 0; jj < 4; ++jj)
                async_lds16(g + jj * 4096 + t * 16, l + jj * 4096 + w * 1024);
        }
        const ushort* Wb = Wbuf + (kk & 1) * 8192;
        short8 af[4], bf[4];
        #pragma unroll
        for (int mt = 0; mt < 4; ++mt)
            af[mt] = ld8(Wb + q * 2048 + (w * 64 + mt * 16 + r) * 8);
        #pragma unroll
        for (int nf = 0; nf < 4; ++nf)
            bf[nf] = ld8(Xs + (nf * 16 + r) * 256 + (((kk * 4 + q) ^ r7) * 8));
        #pragma unroll
        for (int mt = 0; mt < 4; ++mt)
            #pragma unroll
            for (int nf = 0; nf < 4; ++nf)
                acc[mt][nf] = __builtin_amdgcn_mfma_f32_16x16x32_bf16(
                    af[mt], bf[nf], acc[mt][nf], 0, 0, 0);
        __syncthreads();
    }

    float* statS = (float*)Xs;
    float* statQ = statS + 256;
    #pragma unroll
    for (int mt = 0; mt < 4; ++mt) {
        int ob = w * 64 + mt * 16 + q * 4;
        float4 bi = *(const float4*)(bias + ob);
        float sj0 = 0, sj1 = 0, sj2 = 0, sj3 = 0;
        float qj0 = 0, qj1 = 0, qj2 = 0, qj3 = 0;
        #pragma unroll
        for (int nf = 0; nf < 4; ++nf) {
            int n = n0 + nf * 16 + r;
            float v0 = acc[mt][nf][0] + bi.x, v1 = acc[mt][nf][1] + bi.y;
            float v2 = acc[mt][nf][2] + bi.z, v3 = acc[mt][nf][3] + bi.w;
            ushort4 pk; pk.x = f2u(v0); pk.y = f2u(v1); pk.z = f2u(v2); pk.w = f2u(v3);
            *(ushort4*)((ushort*)y + ((size_t)b * N + n) * 256 + ob) = pk;
            sj0 += v0; sj1 += v1; sj2 += v2; sj3 += v3;
            qj0 += v0 * v0; qj1 += v1 * v1; qj2 += v2 * v2; qj3 += v3 * v3;
        }
        #pragma unroll
        for (int m = 1; m <= 8; m <<= 1) {
            sj0 += __shfl_xor(sj0, m); sj1 += __shfl_xor(sj1, m);
            sj2 += __shfl_xor(sj2, m); sj3 += __shfl_xor(sj3, m);
            qj0 += __shfl_xor(qj0, m); qj1 += __shfl_xor(qj1, m);
            qj2 += __shfl_xor(qj2, m); qj3 += __shfl_xor(qj3, m);
        }
        if (r == 0) {
            statS[ob + 0] = sj0; statS[ob + 1] = sj1;
            statS[ob + 2] = sj2; statS[ob + 3] = sj3;
            statQ[ob + 0] = qj0; statQ[ob + 1] = qj1;
            statQ[ob + 2] = qj2; statQ[ob + 3] = qj3;
        }
    }
    __syncthreads();
    atomicAdd(&sums[t], statS[t]);
    atomicAdd(&sums[256 + t], statQ[t]);
}

// ------------- final: BN2+ReLU + transpose to [B,256,N] fp32 (64x64) ------
__global__ __launch_bounds__(256) void final_kernel(
    const __hip_bfloat16* __restrict__ Y, const float* __restrict__ sums2,
    const float* __restrict__ g2, const float* __restrict__ be2,
    float* __restrict__ out)
{
    __shared__ float tl[64][65];
    __shared__ float ssA[64], ssB[64];
    const int t = threadIdx.x;
    const int b = blockIdx.z;
    const int n0 = blockIdx.x * 64, c0 = blockIdx.y * 64;

    if (t < 64) {
        int c = c0 + t;
        float sv = sums2[c], qv = sums2[256 + c];
        float mean = sv * (1.f / 32768.f);
        float var = qv * (1.f / 32768.f) - mean * mean;
        float rstd = rsqrtf(var + 1e-5f);
        float sc = g2[c] * rstd;
        ssA[t] = sc;
        ssB[t] = be2[c] - mean * sc;
    }
    __syncthreads();

    const int nl = t >> 3, cho = 8 * (t & 7);
    #pragma unroll
    for (int it = 0; it < 2; ++it) {
        int n = nl + 32 * it;
        union { short8 s; ushort u[8]; } v;
        v.s = ld8((const ushort*)Y + ((size_t)b * N + n0 + n) * 256 + c0 + cho);
        #pragma unroll
        for (int j = 0; j < 8; ++j)
            tl[n][cho + j] = fmaxf(u2f(v.u[j]) * ssA[cho + j] + ssB[cho + j], 0.f);
    }
    __syncthreads();

    const int cl = t >> 4, n4 = (t & 15) * 4;
    #pragma unroll
    for (int it = 0; it < 4; ++it) {
        int c = cl + 16 * it;
        float4 v;
        v.x = tl[n4 + 0][c]; v.y = tl[n4 + 1][c];
        v.z = tl[n4 + 2][c]; v.w = tl[n4 + 3][c];
        *(float4*)(out + ((size_t)b * 256 + c0 + c) * N + n0 + n4) = v;
    }
}

// ------------------------------------------------------------ launch -----
extern "C" void kernel_launch(void* const* d_in, const int* in_sizes, int n_in,
                              void* d_out, int out_size, void* d_ws, size_t ws_size,
                              hipStream_t stream)
{
    (void)in_sizes; (void)n_in; (void)out_size;
    if (ws_size < (30u << 20)) return;

    const float* pos1 = (const float*)d_in[0];
    const float* pos2 = (const float*)d_in[1];
    const float* f1   = (const float*)d_in[2];
    const float* f2   = (const float*)d_in[3];
    const float* W1   = (const float*)d_in[4];
    const float* b1   = (const float*)d_in[5];
    const float* g1   = (const float*)d_in[6];
    const float* be1  = (const float*)d_in[7];
    const float* W2   = (const float*)d_in[8];
    const float* b2   = (const float*)d_in[9];
    const float* g2   = (const float*)d_in[10];
    const float* be2  = (const float*)d_in[11];

    char* ws = (char*)d_ws;
    int*   idxb  = (int*)(ws + 0);
    float* wgt   = (float*)(ws + 393216);
    float* sums1 = (float*)(ws + 786432);
    float* sums2 = sums1 + 512;
    __hip_bfloat16* W1r = (__hip_bfloat16*)(ws + 819200);
    __hip_bfloat16* W2r = (__hip_bfloat16*)(ws + 1015808);
    float4* p2pack = (float4*)(ws + 1310720);               // 128 KB
    __hip_bfloat16* f2T = (__hip_bfloat16*)(ws + (2u << 20));
    __hip_bfloat16* f1T = (__hip_bfloat16*)(ws + (6u << 20));
    __hip_bfloat16* y   = (__hip_bfloat16*)(ws + (14u << 20));

    prep_kernel<<<116, 256, 0, stream>>>(W1, W2, pos2, W1r, W2r, p2pack, sums1);

    knn_kernel<<<dim3(N / 64, B), 512, 0, stream>>>(pos1, p2pack, wgt, idxb);

    transpose_k<<<dim3(S / 64, 256 / 64, B), 256, 0, stream>>>(f2, f2T, S, 256);
    transpose_k<<<dim3(N / 64, 128 / 64, B), 256, 0, stream>>>(f1, f1T, N, 128);

    gemm1_kernel<<<dim3(N / 64, B), 256, 0, stream>>>(
        W1r, b1, f2T, f1T, idxb, wgt, y, sums1);
    gemm2_kernel<<<dim3(N / 64, B), 256, 0, stream>>>(
        W2r, b2, sums1, g1, be1, y, sums2);
    final_kernel<<<dim3(N / 64, 256 / 64, B), 256, 0, stream>>>(
        y, sums2, g2, be2, (float*)d_out);
}